// Round 5
// baseline (7377.647 us; speedup 1.0000x reference)
//
#include <hip/hip_runtime.h>
#include <cstdint>

// MTNN: static MLP + dyn proj + biRNN(relu) + routed per-trial dot.
// B=512,T=200,SI=100,DI=68,HS=256,HD=128,D=512,K=1.
// Inputs fp32, neuron_order int32, OUTPUT fp32 (reference dtypes).
// R4 post-mortem: R3's math was correct; the only bug was writing bf16 u16
// into the fp32 d_out buffer (half-filled buffer -> absmax == max|ref|).
constexpr int B = 512, T = 200, SI = 100, DI = 68, HS = 256, HD = 128, D = 512;

#define DEV __device__ __forceinline__

DEV float lo2f(unsigned int w) { return __builtin_bit_cast(float, w << 16); }
DEV float hi2f(unsigned int w) { return __builtin_bit_cast(float, w & 0xffff0000u); }
DEV unsigned short f2bf(float f) {
    unsigned int x = __builtin_bit_cast(unsigned int, f);
    x += 0x7fffu + ((x >> 16) & 1u);   // RNE
    return (unsigned short)(x >> 16);
}
DEV unsigned int pack2bf(float a, float b) {
    return (unsigned int)f2bf(a) | ((unsigned int)f2bf(b) << 16);
}

// ---------------- K1: static branch + static segment of routed dot ----------
// s = relu(relu(x@W1^T+b1)@W2^T+b2); statd[b] = s . Wn[n_b, 0:256] + bn[n_b]
__global__ __launch_bounds__(256) void k_static(
    const float* __restrict__ xs_g, const float* __restrict__ w1,
    const float* __restrict__ b1, const float* __restrict__ w2,
    const float* __restrict__ b2, const int* __restrict__ norder,
    const float* __restrict__ nw, const float* __restrict__ nb,
    float* __restrict__ statd)
{
    __shared__ __align__(16) float xs[SI];
    __shared__ __align__(16) float s1[HS];
    __shared__ __align__(16) float red[256];
    int b = blockIdx.x, t = threadIdx.x;
    if (t < SI) xs[t] = xs_g[b * SI + t];
    __syncthreads();
    // layer 1: thread t computes s1[t]
    float a = b1[t];
    const float4* w = (const float4*)(w1 + t * SI);  // 400t bytes -> 16B aligned
    const float4* xp4 = (const float4*)xs;
    #pragma unroll
    for (int i = 0; i < SI / 4; ++i) {
        float4 ww = w[i];
        float4 xx = xp4[i];
        a += xx.x * ww.x + xx.y * ww.y + xx.z * ww.z + xx.w * ww.w;
    }
    s1[t] = fmaxf(a, 0.f);
    __syncthreads();
    // layer 2
    float a2 = b2[t];
    const float4* w2p = (const float4*)(w2 + t * HS);
    const float4* s1p = (const float4*)s1;
    #pragma unroll 8
    for (int i = 0; i < HS / 4; ++i) {
        float4 ww = w2p[i];
        float4 s = s1p[i];
        a2 += s.x * ww.x + s.y * ww.y + s.z * ww.z + s.w * ww.w;
    }
    float sv = fmaxf(a2, 0.f);
    // static segment of routed dot: d-index == t (0..255)
    int n = norder[b];
    red[t] = sv * nw[(size_t)n * D + t];
    __syncthreads();
    for (int s = 128; s > 0; s >>= 1) {
        if (t < s) red[t] += red[t + s];
        __syncthreads();
    }
    if (t == 0) statd[b] = red[0] + nb[n];
}

// ---------------- K2: fully-fused persistent scan ---------------------------
// Per block: one direction, 4 batch rows. Per step t:
//   P2: d = relu(Wdyn x_t + bd)            (weights bf16-packed in registers)
//   P3: a = relu(Wih d + Whh h_{t-1} + bi)
//   P4: acc[b,t] = h_t . Wn[n_b, seg]      (wave shuffle reduce)
__global__ __launch_bounds__(256, 1) void k_scan(
    const float* __restrict__ xd,
    const float* __restrict__ wdyn_g, const float* __restrict__ bdyn_g,
    const float* __restrict__ wihf, const float* __restrict__ whhf,
    const float* __restrict__ bihf, const float* __restrict__ bhhf,
    const float* __restrict__ wihb, const float* __restrict__ whhb,
    const float* __restrict__ bihb, const float* __restrict__ bhhb,
    const int* __restrict__ norder, const float* __restrict__ nw,
    float* __restrict__ accf, float* __restrict__ accb)
{
    __shared__ __align__(16) float hbuf[4][132];   // row stride 528 B (16B aligned)
    __shared__ __align__(16) float dbuf[4][132];
    __shared__ __align__(16) float xrow[4][68];
    __shared__ __align__(16) float wn[4][HD];
    __shared__ __align__(16) float biasd[HD];
    __shared__ __align__(16) float biasi[HD];

    int tid = threadIdx.x;
    int dir = blockIdx.x >> 7, b0 = (blockIdx.x & 127) * 4;
    const float* wih_g = dir ? wihb : wihf;
    const float* whh_g = dir ? whhb : whhf;
    const float* bih_g = dir ? bihb : bihf;
    const float* bhh_g = dir ? bhhb : bhhf;
    float* acc = dir ? accb : accf;
    int segoff = dir ? (HS + HD) : HS;   // 384 : 256

    int o = tid & 127;
    // per-thread weight rows, packed fp32 -> bf16x2 (register budget: 162 uints)
    unsigned int rdyn[DI / 2], rih[HD / 2], rhh[HD / 2];
    {
        const float2* p1 = (const float2*)(wdyn_g + o * DI);  // 272o bytes, 8B aligned
        #pragma unroll
        for (int i = 0; i < DI / 2; ++i) { float2 v = p1[i]; rdyn[i] = pack2bf(v.x, v.y); }
        const float2* p2 = (const float2*)(wih_g + o * HD);
        #pragma unroll
        for (int i = 0; i < HD / 2; ++i) { float2 v = p2[i]; rih[i] = pack2bf(v.x, v.y); }
        const float2* p3 = (const float2*)(whh_g + o * HD);
        #pragma unroll
        for (int i = 0; i < HD / 2; ++i) { float2 v = p3[i]; rhh[i] = pack2bf(v.x, v.y); }
    }
    if (tid < HD) {
        biasd[tid] = bdyn_g[tid];
        biasi[tid] = bih_g[tid] + bhh_g[tid];
    }
    for (int idx = tid; idx < 4 * HD; idx += 256) {
        int r = idx >> 7, c = idx & 127;
        wn[r][c] = nw[(size_t)norder[b0 + r] * D + segoff + c];
    }
    for (int idx = tid; idx < 4 * 132; idx += 256) ((float*)hbuf)[idx] = 0.f;

    int t0 = dir ? (T - 1) : 0, dt = dir ? -1 : 1;
    // initial x load: 4 rows x 68 floats by 136 threads (float2 each)
    bool xact = tid < 136;
    int xr = 0, xc = 0;
    if (xact) { xr = tid / 34; xc = tid - xr * 34; }
    if (xact) {
        float2 v = *((const float2*)(xd + ((size_t)(b0 + xr) * T + t0) * DI) + xc);
        xrow[xr][2 * xc] = v.x;
        xrow[xr][2 * xc + 1] = v.y;
    }
    __syncthreads();

    int rhalf = tid >> 7, r0 = rhalf * 2, r1 = r0 + 1;
    const float2* x0p = (const float2*)xrow[r0];
    const float2* x1p = (const float2*)xrow[r1];
    const float4* d0p = (const float4*)dbuf[r0];
    const float4* d1p = (const float4*)dbuf[r1];
    const float4* h0p = (const float4*)hbuf[r0];
    const float4* h1p = (const float4*)hbuf[r1];
    int t = t0;
    for (int step = 0; step < T; ++step) {
        // P2: dynamic-input projection
        float dv0 = biasd[o], dv1 = biasd[o];
        #pragma unroll
        for (int i = 0; i < DI / 2; ++i) {
            float wl = lo2f(rdyn[i]), wh = hi2f(rdyn[i]);
            float2 a = x0p[i], b = x1p[i];
            dv0 += a.x * wl + a.y * wh;
            dv1 += b.x * wl + b.y * wh;
        }
        dbuf[r0][o] = fmaxf(dv0, 0.f);
        dbuf[r1][o] = fmaxf(dv1, 0.f);
        // prefetch next x into registers (latency hidden by P3 MAC)
        int tn = t + dt;
        float2 px = make_float2(0.f, 0.f);
        if (xact && step + 1 < T)
            px = *((const float2*)(xd + ((size_t)(b0 + xr) * T + tn) * DI) + xc);
        __syncthreads();   // A: dbuf visible; xrow consumed
        // P3: ih-proj + recurrence
        float a0 = biasi[o], a1 = biasi[o];
        #pragma unroll
        for (int i = 0; i < HD / 4; ++i) {
            unsigned int wi0 = rih[2 * i], wi1 = rih[2 * i + 1];
            unsigned int wh0 = rhh[2 * i], wh1 = rhh[2 * i + 1];
            float4 dd0 = d0p[i], dd1 = d1p[i];
            float4 hh0 = h0p[i], hh1 = h1p[i];
            a0 += dd0.x * lo2f(wi0) + dd0.y * hi2f(wi0) + dd0.z * lo2f(wi1) + dd0.w * hi2f(wi1);
            a1 += dd1.x * lo2f(wi0) + dd1.y * hi2f(wi0) + dd1.z * lo2f(wi1) + dd1.w * hi2f(wi1);
            a0 += hh0.x * lo2f(wh0) + hh0.y * hi2f(wh0) + hh0.z * lo2f(wh1) + hh0.w * hi2f(wh1);
            a1 += hh1.x * lo2f(wh0) + hh1.y * hi2f(wh0) + hh1.z * lo2f(wh1) + hh1.w * hi2f(wh1);
        }
        a0 = fmaxf(a0, 0.f);
        a1 = fmaxf(a1, 0.f);
        if (xact && step + 1 < T) {
            xrow[xr][2 * xc] = px.x;
            xrow[xr][2 * xc + 1] = px.y;
        }
        __syncthreads();   // B: hbuf/dbuf reads done
        hbuf[r0][o] = a0;
        hbuf[r1][o] = a1;
        __syncthreads();   // C: h_t visible
        // P4: routed-dot segment (wave rr reduces row rr)
        int rr = tid >> 6, l = tid & 63;
        float p = hbuf[rr][l] * wn[rr][l] + hbuf[rr][l + 64] * wn[rr][l + 64];
        #pragma unroll
        for (int off = 32; off; off >>= 1) p += __shfl_xor(p, off);
        if (l == 0) acc[(size_t)(b0 + rr) * T + t] = p;
        t = tn;
    }
}

// ---------------- K3: out = relu(statd[b] + accf + accb) -> FP32 ------------
__global__ __launch_bounds__(256) void k_final(
    const float* __restrict__ statd, const float* __restrict__ accf,
    const float* __restrict__ accb, float* __restrict__ out)
{
    int idx = blockIdx.x * 256 + threadIdx.x;
    if (idx < B * T) {
        int b = idx / T;
        float v = statd[b] + accf[idx] + accb[idx];
        out[idx] = fmaxf(v, 0.f);   // fp32 write — the R3/R4 bug was bf16 here
    }
}

extern "C" void kernel_launch(void* const* d_in, const int* in_sizes, int n_in,
                              void* d_out, int out_size, void* d_ws, size_t ws_size,
                              hipStream_t stream)
{
    const float* x_static  = (const float*)d_in[0];
    const float* x_dynamic = (const float*)d_in[1];
    const int*   norder    = (const int*)d_in[2];
    const float* w_s1   = (const float*)d_in[3];
    const float* b_s1   = (const float*)d_in[4];
    const float* w_s2   = (const float*)d_in[5];
    const float* b_s2   = (const float*)d_in[6];
    const float* w_dyn  = (const float*)d_in[7];
    const float* b_dyn  = (const float*)d_in[8];
    const float* w_ih_f = (const float*)d_in[9];
    const float* w_hh_f = (const float*)d_in[10];
    const float* b_ih_f = (const float*)d_in[11];
    const float* b_hh_f = (const float*)d_in[12];
    const float* w_ih_b = (const float*)d_in[13];
    const float* w_hh_b = (const float*)d_in[14];
    const float* b_ih_b = (const float*)d_in[15];
    const float* b_hh_b = (const float*)d_in[16];
    const float* nw     = (const float*)d_in[17];
    const float* nb     = (const float*)d_in[18];
    float* out = (float*)d_out;

    // workspace: statd (2 KB) + accf/accb (400 KB each)
    char* ws = (char*)d_ws;
    float* statd = (float*)ws;                       // 512 floats
    float* accf  = (float*)(ws + 2048);              // B*T floats
    float* accb  = (float*)(ws + 2048 + (size_t)B * T * 4);

    hipLaunchKernelGGL(k_static, dim3(B), dim3(256), 0, stream,
                       x_static, w_s1, b_s1, w_s2, b_s2, norder, nw, nb, statd);
    hipLaunchKernelGGL(k_scan, dim3(256), dim3(256), 0, stream,
                       x_dynamic, w_dyn, b_dyn,
                       w_ih_f, w_hh_f, b_ih_f, b_hh_f,
                       w_ih_b, w_hh_b, b_ih_b, b_hh_b,
                       norder, nw, accf, accb);
    hipLaunchKernelGGL(k_final, dim3((B * T + 255) / 256), dim3(256), 0, stream,
                       statd, accf, accb, out);
}

// Round 6
// 767.842 us; speedup vs baseline: 9.6083x; 9.6083x over previous
//
#include <hip/hip_runtime.h>
#include <cstdint>

// MTNN: static MLP + dyn proj + biRNN(relu) + routed per-trial dot.
// B=512,T=200,SI=100,DI=68,HS=256,HD=128,D=512,K=1. fp32 in, fp32 out.
// R5 lesson: 162-dword per-thread weight arrays -> scratch spill -> 9.4 GB/disp
// scratch FETCH. This version caps per-thread weight arrays at <=84 dwords and
// moves the parallel projections (d, xw) out of the sequential scan.
constexpr int B = 512, T = 200, SI = 100, DI = 68, HS = 256, HD = 128, D = 512;
constexpr int BT = B * T;            // 102400 rows
constexpr int XPAD = 80;             // padded x row (floats); cols 68..79 = 0

#define DEV __device__ __forceinline__

DEV float lo2f(unsigned int w) { return __builtin_bit_cast(float, w << 16); }
DEV float hi2f(unsigned int w) { return __builtin_bit_cast(float, w & 0xffff0000u); }
DEV unsigned short f2bf(float f) {
    unsigned int x = __builtin_bit_cast(unsigned int, f);
    x += 0x7fffu + ((x >> 16) & 1u);   // RNE
    return (unsigned short)(x >> 16);
}
DEV unsigned int pack2bf(float a, float b) {
    return (unsigned int)f2bf(a) | ((unsigned int)f2bf(b) << 16);
}
DEV float bf2f(unsigned short u) {
    return __builtin_bit_cast(float, ((unsigned int)u) << 16);
}
// a += dot(8 bf16 packed in w, 8 floats in xa|xb)
DEV float fma8u(float a, uint4 w, float4 xa, float4 xb) {
    a += xa.x * lo2f(w.x) + xa.y * hi2f(w.x) + xa.z * lo2f(w.y) + xa.w * hi2f(w.y);
    a += xb.x * lo2f(w.z) + xb.y * hi2f(w.z) + xb.z * lo2f(w.w) + xb.w * hi2f(w.w);
    return a;
}
// a += dot(8 bf16 in w, 8 bf16 in d)
DEV float fma8uu(float a, uint4 w, uint4 d) {
    a += lo2f(d.x) * lo2f(w.x) + hi2f(d.x) * hi2f(w.x)
       + lo2f(d.y) * lo2f(w.y) + hi2f(d.y) * hi2f(w.y);
    a += lo2f(d.z) * lo2f(w.z) + hi2f(d.z) * hi2f(w.z)
       + lo2f(d.w) * lo2f(w.w) + hi2f(d.w) * hi2f(w.w);
    return a;
}

// ---------------- K1: static branch + static segment of routed dot ----------
__global__ __launch_bounds__(256) void k_static(
    const float* __restrict__ xs_g, const float* __restrict__ w1,
    const float* __restrict__ b1, const float* __restrict__ w2,
    const float* __restrict__ b2, const int* __restrict__ norder,
    const float* __restrict__ nw, const float* __restrict__ nb,
    float* __restrict__ statd)
{
    __shared__ __align__(16) float xs[SI];
    __shared__ __align__(16) float s1[HS];
    __shared__ __align__(16) float red[256];
    int b = blockIdx.x, t = threadIdx.x;
    if (t < SI) xs[t] = xs_g[b * SI + t];
    __syncthreads();
    float a = b1[t];
    const float4* w = (const float4*)(w1 + t * SI);
    const float4* xp4 = (const float4*)xs;
    #pragma unroll
    for (int i = 0; i < SI / 4; ++i) {
        float4 ww = w[i]; float4 xx = xp4[i];
        a += xx.x * ww.x + xx.y * ww.y + xx.z * ww.z + xx.w * ww.w;
    }
    s1[t] = fmaxf(a, 0.f);
    __syncthreads();
    float a2 = b2[t];
    const float4* w2p = (const float4*)(w2 + t * HS);
    const float4* s1p = (const float4*)s1;
    #pragma unroll 8
    for (int i = 0; i < HS / 4; ++i) {
        float4 ww = w2p[i]; float4 s = s1p[i];
        a2 += s.x * ww.x + s.y * ww.y + s.z * ww.z + s.w * ww.w;
    }
    float sv = fmaxf(a2, 0.f);
    int n = norder[b];
    red[t] = sv * nw[(size_t)n * D + t];
    __syncthreads();
    for (int s = 128; s > 0; s >>= 1) {
        if (t < s) red[t] += red[t + s];
        __syncthreads();
    }
    if (t == 0) statd[b] = red[0] + nb[n];
}

// ---------------- K2: d + ih-projection for both dirs (parallel pass) -------
// thread (o = tid&127, z = tid>>7). z splits P2's input half; z = dir in P3.
// Per row: d[o] = relu(Wdyn x + bd) (LDS bf16), xw[z][row][o] = Wih_z d + bias_z.
__global__ __launch_bounds__(256) void k_dxw(
    const float* __restrict__ xd,
    const float* __restrict__ wdyn, const float* __restrict__ bdyn,
    const float* __restrict__ wihf, const float* __restrict__ bihf,
    const float* __restrict__ bhhf,
    const float* __restrict__ wihb, const float* __restrict__ bihb,
    const float* __restrict__ bhhb,
    unsigned short* __restrict__ xw)
{
    __shared__ __align__(16) float xs[XPAD];
    __shared__ __align__(16) float ppd[2][HD];
    __shared__ __align__(16) unsigned int dpk[HD / 2];   // d row, bf16-packed
    __shared__ __align__(16) float biasd[HD];
    __shared__ __align__(16) float bx[2][HD];

    int tid = threadIdx.x, o = tid & 127, z = tid >> 7;
    // P2 weights: wdyn row o, x-cols [z*40, z*40+40) (cols >=68 are zero-pad)
    uint4 wd[5];
    #pragma unroll
    for (int i = 0; i < 5; ++i) {
        float v[8];
        #pragma unroll
        for (int j = 0; j < 8; ++j) {
            int c = z * 40 + 8 * i + j;
            v[j] = (c < DI) ? wdyn[o * DI + c] : 0.f;
        }
        wd[i].x = pack2bf(v[0], v[1]); wd[i].y = pack2bf(v[2], v[3]);
        wd[i].z = pack2bf(v[4], v[5]); wd[i].w = pack2bf(v[6], v[7]);
    }
    // P3 weights: wih_z row o (128 floats), split into two 8-uint4 arrays
    const float* wsrc = z ? (wihb + o * HD) : (wihf + o * HD);
    uint4 wiA[8], wiB[8];
    #pragma unroll
    for (int i = 0; i < 8; ++i) {
        const float* p = wsrc + 8 * i;
        wiA[i].x = pack2bf(p[0], p[1]); wiA[i].y = pack2bf(p[2], p[3]);
        wiA[i].z = pack2bf(p[4], p[5]); wiA[i].w = pack2bf(p[6], p[7]);
        const float* q = wsrc + 64 + 8 * i;
        wiB[i].x = pack2bf(q[0], q[1]); wiB[i].y = pack2bf(q[2], q[3]);
        wiB[i].z = pack2bf(q[4], q[5]); wiB[i].w = pack2bf(q[6], q[7]);
    }
    if (tid < HD) {
        biasd[tid] = bdyn[tid];
        bx[0][tid] = bihf[tid] + bhhf[tid];
        bx[1][tid] = bihb[tid] + bhhb[tid];
    }
    if (tid < XPAD - DI) xs[DI + tid] = 0.f;   // zero pad cols 68..79
    int row = blockIdx.x, gs = gridDim.x;
    if (tid < DI) xs[tid] = xd[(size_t)row * DI + tid];   // initial stage

    for (; row < BT; row += gs) {
        __syncthreads();   // A: xs ready; dpk from prev iter fully consumed
        // P2: partial dot over this z's x-half
        float pp = 0.f;
        const float4* xp = (const float4*)(xs + z * 40);  // 160B offset, aligned
        #pragma unroll
        for (int i = 0; i < 5; ++i)
            pp = fma8u(pp, wd[i], xp[2 * i], xp[2 * i + 1]);
        ppd[z][o] = pp;
        // prefetch next row's x
        float px = 0.f;
        bool nv = (row + gs < BT) && (tid < DI);
        if (nv) px = xd[(size_t)(row + gs) * DI + tid];
        __syncthreads();   // B: ppd visible
        if (z == 0) {
            float dv = fmaxf(ppd[0][o] + ppd[1][o] + biasd[o], 0.f);
            ((unsigned short*)dpk)[o] = f2bf(dv);
        }
        __syncthreads();   // C: dpk visible; ppd/xs free
        if (nv) xs[tid] = px;   // stage next x (consumed only after next A)
        // P3: xw = Wih_z d + bias_z
        float a = bx[z][o];
        const uint4* dp = (const uint4*)dpk;
        #pragma unroll
        for (int i = 0; i < 8; ++i) a = fma8uu(a, wiA[i], dp[i]);
        #pragma unroll
        for (int i = 0; i < 8; ++i) a = fma8uu(a, wiB[i], dp[8 + i]);
        xw[((size_t)z * BT + row) * HD + o] = f2bf(a);
    }
}

// ---------------- K3: recurrence-only scan + fused routed-dot ---------------
// 256 blocks: dir = bid>>7, 4 batch rows each. thread (o, half) -> rows 2h,2h+1.
// whh row in 16 uint4 regs (64 dwords — spill-safe). h bf16-packed in LDS.
__global__ __launch_bounds__(256) void k_scan(
    const unsigned short* __restrict__ xw,
    const float* __restrict__ whhf, const float* __restrict__ whhb,
    const int* __restrict__ norder, const float* __restrict__ nw,
    float* __restrict__ accf, float* __restrict__ accb)
{
    __shared__ __align__(16) unsigned short hpk[4][136];  // 272B row stride
    __shared__ __align__(16) float wn[4][HD];

    int tid = threadIdx.x, o = tid & 127, half = tid >> 7;
    int dir = blockIdx.x >> 7, b0 = (blockIdx.x & 127) * 4;
    const float* whh = dir ? whhb : whhf;
    const unsigned short* xwp = xw + (size_t)dir * BT * HD;
    float* acc = dir ? accb : accf;
    int segoff = dir ? (HS + HD) : HS;   // 384 : 256

    // whh row o -> two 8-uint4 register arrays
    uint4 wA[8], wB[8];
    #pragma unroll
    for (int i = 0; i < 8; ++i) {
        const float* p = whh + o * HD + 8 * i;
        wA[i].x = pack2bf(p[0], p[1]); wA[i].y = pack2bf(p[2], p[3]);
        wA[i].z = pack2bf(p[4], p[5]); wA[i].w = pack2bf(p[6], p[7]);
        const float* q = whh + o * HD + 64 + 8 * i;
        wB[i].x = pack2bf(q[0], q[1]); wB[i].y = pack2bf(q[2], q[3]);
        wB[i].z = pack2bf(q[4], q[5]); wB[i].w = pack2bf(q[6], q[7]);
    }
    for (int idx = tid; idx < 4 * HD; idx += 256) {
        int r = idx >> 7, c = idx & 127;
        wn[r][c] = nw[(size_t)norder[b0 + r] * D + segoff + c];
    }
    for (int idx = tid; idx < 4 * 136; idx += 256) hpk[idx / 136][idx % 136] = 0;
    __syncthreads();

    int r0 = half * 2, r1 = r0 + 1;
    size_t base0 = ((size_t)(b0 + r0) * T) * HD + o;
    size_t base1 = ((size_t)(b0 + r1) * T) * HD + o;
    int t = dir ? (T - 1) : 0, dt = dir ? -1 : 1;
    unsigned short x0 = xwp[base0 + (size_t)t * HD];
    unsigned short x1 = xwp[base1 + (size_t)t * HD];
    const uint4* h0 = (const uint4*)hpk[r0];
    const uint4* h1 = (const uint4*)hpk[r1];

    for (int step = 0; step < T; ++step) {
        float a0 = bf2f(x0), a1 = bf2f(x1);   // xw already includes b_ih+b_hh
        #pragma unroll
        for (int i = 0; i < 8; ++i) {
            uint4 ww = wA[i]; uint4 u0 = h0[i], u1 = h1[i];
            a0 = fma8uu(a0, ww, u0);
            a1 = fma8uu(a1, ww, u1);
        }
        #pragma unroll
        for (int i = 0; i < 8; ++i) {
            uint4 ww = wB[i]; uint4 u0 = h0[8 + i], u1 = h1[8 + i];
            a0 = fma8uu(a0, ww, u0);
            a1 = fma8uu(a1, ww, u1);
        }
        a0 = fmaxf(a0, 0.f);
        a1 = fmaxf(a1, 0.f);
        int tn = t + dt;
        unsigned short px0 = 0, px1 = 0;
        if (step + 1 < T) {   // prefetch next xw
            px0 = xwp[base0 + (size_t)tn * HD];
            px1 = xwp[base1 + (size_t)tn * HD];
        }
        __syncthreads();   // all reads of h_{t-1} done (incl. prev P4)
        hpk[r0][o] = f2bf(a0);
        hpk[r1][o] = f2bf(a1);
        __syncthreads();   // h_t visible
        // P4: routed-dot segment (wave rr reduces row rr)
        int rr = tid >> 6, l = tid & 63;
        float p = bf2f(hpk[rr][l]) * wn[rr][l] + bf2f(hpk[rr][l + 64]) * wn[rr][l + 64];
        #pragma unroll
        for (int off = 32; off; off >>= 1) p += __shfl_xor(p, off);
        if (l == 0) acc[(size_t)(b0 + rr) * T + t] = p;
        x0 = px0; x1 = px1; t = tn;
    }
}

// ---------------- K4: out = relu(statd[b] + accf + accb) -> FP32 ------------
__global__ __launch_bounds__(256) void k_final(
    const float* __restrict__ statd, const float* __restrict__ accf,
    const float* __restrict__ accb, float* __restrict__ out)
{
    int idx = blockIdx.x * 256 + threadIdx.x;
    if (idx < BT) {
        int b = idx / T;
        out[idx] = fmaxf(statd[b] + accf[idx] + accb[idx], 0.f);
    }
}

extern "C" void kernel_launch(void* const* d_in, const int* in_sizes, int n_in,
                              void* d_out, int out_size, void* d_ws, size_t ws_size,
                              hipStream_t stream)
{
    const float* x_static  = (const float*)d_in[0];
    const float* x_dynamic = (const float*)d_in[1];
    const int*   norder    = (const int*)d_in[2];
    const float* w_s1   = (const float*)d_in[3];
    const float* b_s1   = (const float*)d_in[4];
    const float* w_s2   = (const float*)d_in[5];
    const float* b_s2   = (const float*)d_in[6];
    const float* w_dyn  = (const float*)d_in[7];
    const float* b_dyn  = (const float*)d_in[8];
    const float* w_ih_f = (const float*)d_in[9];
    const float* w_hh_f = (const float*)d_in[10];
    const float* b_ih_f = (const float*)d_in[11];
    const float* b_hh_f = (const float*)d_in[12];
    const float* w_ih_b = (const float*)d_in[13];
    const float* w_hh_b = (const float*)d_in[14];
    const float* b_ih_b = (const float*)d_in[15];
    const float* b_hh_b = (const float*)d_in[16];
    const float* nw     = (const float*)d_in[17];
    const float* nb     = (const float*)d_in[18];
    float* out = (float*)d_out;

    // ws: statd 2KB | accf 400KB | accb 400KB | xw 52.4MB  (total ~53.3MB)
    char* ws = (char*)d_ws;
    float* statd = (float*)ws;
    float* accf  = (float*)(ws + 2048);
    float* accb  = (float*)(ws + 2048 + (size_t)BT * 4);
    unsigned short* xw = (unsigned short*)(ws + 2048 + (size_t)BT * 8);

    hipLaunchKernelGGL(k_static, dim3(B), dim3(256), 0, stream,
                       x_static, w_s1, b_s1, w_s2, b_s2, norder, nw, nb, statd);
    hipLaunchKernelGGL(k_dxw, dim3(1024), dim3(256), 0, stream,
                       x_dynamic, w_dyn, b_dyn,
                       w_ih_f, b_ih_f, b_hh_f, w_ih_b, b_ih_b, b_hh_b, xw);
    hipLaunchKernelGGL(k_scan, dim3(256), dim3(256), 0, stream,
                       xw, w_hh_f, w_hh_b, norder, nw, accf, accb);
    hipLaunchKernelGGL(k_final, dim3((BT + 255) / 256), dim3(256), 0, stream,
                       statd, accf, accb, out);
}

// Round 7
// 473.832 us; speedup vs baseline: 15.5702x; 1.6205x over previous
//
#include <hip/hip_runtime.h>
#include <cstdint>

// MTNN: static MLP + dyn proj + biRNN(relu) + routed per-trial dot.
// B=512,T=200,SI=100,DI=68,HS=256,HD=128,D=512,K=1. fp32 in, fp32 out.
// R6->R7: k_dxw moved to MFMA (16x16x32 bf16); k_scan de-unpacked (fp32
// weights in VGPRs, fp32 h in LDS broadcast) with 1 row-scan per block.
constexpr int B = 512, T = 200, SI = 100, DI = 68, HS = 256, HD = 128, D = 512;
constexpr int BT = B * T;   // 102400

typedef __attribute__((ext_vector_type(8))) short short8;    // 8 bf16 (4 VGPRs)
typedef __attribute__((ext_vector_type(4))) float floatx4;   // MFMA C/D

#define DEV __device__ __forceinline__

DEV unsigned short f2bf(float f) {
    unsigned int x = __builtin_bit_cast(unsigned int, f);
    x += 0x7fffu + ((x >> 16) & 1u);   // RNE
    return (unsigned short)(x >> 16);
}
DEV float bf2f(unsigned short u) {
    return __builtin_bit_cast(float, ((unsigned int)u) << 16);
}
// 8 consecutive fp32 -> bf16 MFMA fragment
DEV short8 ldfrag(const float* p0) {
    const float4* p = (const float4*)p0;
    float4 v0 = p[0], v1 = p[1];
    short8 r;
    r[0] = (short)f2bf(v0.x); r[1] = (short)f2bf(v0.y);
    r[2] = (short)f2bf(v0.z); r[3] = (short)f2bf(v0.w);
    r[4] = (short)f2bf(v1.x); r[5] = (short)f2bf(v1.y);
    r[6] = (short)f2bf(v1.z); r[7] = (short)f2bf(v1.w);
    return r;
}

// ---------------- K1: static branch + static segment of routed dot ----------
__global__ __launch_bounds__(256) void k_static(
    const float* __restrict__ xs_g, const float* __restrict__ w1,
    const float* __restrict__ b1, const float* __restrict__ w2,
    const float* __restrict__ b2, const int* __restrict__ norder,
    const float* __restrict__ nw, const float* __restrict__ nb,
    float* __restrict__ statd)
{
    __shared__ __align__(16) float xs[SI];
    __shared__ __align__(16) float s1[HS];
    __shared__ __align__(16) float red[256];
    int b = blockIdx.x, t = threadIdx.x;
    if (t < SI) xs[t] = xs_g[b * SI + t];
    __syncthreads();
    float a = b1[t];
    const float4* w = (const float4*)(w1 + t * SI);
    const float4* xp4 = (const float4*)xs;
    #pragma unroll
    for (int i = 0; i < SI / 4; ++i) {
        float4 ww = w[i]; float4 xx = xp4[i];
        a += xx.x * ww.x + xx.y * ww.y + xx.z * ww.z + xx.w * ww.w;
    }
    s1[t] = fmaxf(a, 0.f);
    __syncthreads();
    float a2 = b2[t];
    const float4* w2p = (const float4*)(w2 + t * HS);
    const float4* s1p = (const float4*)s1;
    #pragma unroll 8
    for (int i = 0; i < HS / 4; ++i) {
        float4 ww = w2p[i]; float4 s = s1p[i];
        a2 += s.x * ww.x + s.y * ww.y + s.z * ww.z + s.w * ww.w;
    }
    float sv = fmaxf(a2, 0.f);
    int n = norder[b];
    red[t] = sv * nw[(size_t)n * D + t];
    __syncthreads();
    for (int s = 128; s > 0; s >>= 1) {
        if (t < s) red[t] += red[t + s];
        __syncthreads();
    }
    if (t == 0) statd[b] = red[0] + nb[n];
}

// ---------------- K2: d + ih-projection via MFMA ----------------------------
// 1600 blocks x 256 thr (4 waves). Block = 64 BT-rows; wave w owns rows
// [w*16, w*16+16). P2: d = relu(x @ Wdyn^T + bd)  (K=68 zero-padded to 96),
// P3: xw_z = d @ Wih_z^T + (bih_z+bhh_z), z=0(fwd),1(bwd). bf16 MFMA, fp32 acc.
__global__ __launch_bounds__(256) void k_dxw(
    const float* __restrict__ xd,
    const float* __restrict__ wdyn, const float* __restrict__ bdyn,
    const float* __restrict__ wihf, const float* __restrict__ bihf,
    const float* __restrict__ bhhf,
    const float* __restrict__ wihb, const float* __restrict__ bihb,
    const float* __restrict__ bhhb,
    unsigned short* __restrict__ xw)
{
    __shared__ __align__(16) unsigned short xb[64][104];  // x bf16, K 0..95 (+pad)
    __shared__ __align__(16) unsigned short dl[64][136];  // d bf16, 128 cols (+pad)
    int tid = threadIdx.x;
    int R0 = blockIdx.x * 64;
    // zero (covers the K-pad cols), then fill real x
    for (int i = tid; i < 64 * 104; i += 256) ((unsigned short*)xb)[i] = 0;
    __syncthreads();
    for (int i = tid; i < 64 * DI; i += 256) {
        int r = i / DI, c = i - r * DI;
        xb[r][c] = f2bf(xd[(size_t)(R0 + r) * DI + c]);
    }
    __syncthreads();

    int lane = tid & 63, w = tid >> 6;
    int ln = lane & 15, q = lane >> 4;

    // ---- P2 ----
    short8 af[3];
    #pragma unroll
    for (int c = 0; c < 3; ++c)
        af[c] = *(const short8*)&xb[w * 16 + ln][c * 32 + q * 8];
    #pragma unroll
    for (int j = 0; j < 8; ++j) {
        int n = j * 16 + ln;
        floatx4 a = {0.f, 0.f, 0.f, 0.f};
        #pragma unroll
        for (int c = 0; c < 3; ++c) {
            int k0 = c * 32 + q * 8;
            short8 bf;
            if (k0 + 8 <= DI) {
                bf = ldfrag(wdyn + (size_t)n * DI + k0);
            } else {
                #pragma unroll
                for (int e = 0; e < 8; ++e) {
                    int k = k0 + e;
                    bf[e] = (k < DI) ? (short)f2bf(wdyn[(size_t)n * DI + k]) : (short)0;
                }
            }
            a = __builtin_amdgcn_mfma_f32_16x16x32_bf16(af[c], bf, a, 0, 0, 0);
        }
        float bd = bdyn[n];
        #pragma unroll
        for (int r = 0; r < 4; ++r) {
            float v = fmaxf(a[r] + bd, 0.f);              // C/D: row=q*4+r, col=n
            dl[w * 16 + q * 4 + r][n] = f2bf(v);
        }
    }
    __syncthreads();

    // ---- P3 (both directions) ----
    short8 df[4];
    #pragma unroll
    for (int c = 0; c < 4; ++c)
        df[c] = *(const short8*)&dl[w * 16 + ln][c * 32 + q * 8];
    #pragma unroll
    for (int z = 0; z < 2; ++z) {
        const float* wih = z ? wihb : wihf;
        const float* bi  = z ? bihb : bihf;
        const float* bh  = z ? bhhb : bhhf;
        unsigned short* outp = xw + (size_t)z * BT * HD;
        #pragma unroll
        for (int j = 0; j < 8; ++j) {
            int n = j * 16 + ln;
            floatx4 a = {0.f, 0.f, 0.f, 0.f};
            #pragma unroll
            for (int c = 0; c < 4; ++c) {
                short8 bf = ldfrag(wih + (size_t)n * HD + c * 32 + q * 8);
                a = __builtin_amdgcn_mfma_f32_16x16x32_bf16(df[c], bf, a, 0, 0, 0);
            }
            float bias = bi[n] + bh[n];
            #pragma unroll
            for (int r = 0; r < 4; ++r) {
                int row = R0 + w * 16 + q * 4 + r;
                outp[(size_t)row * HD + n] = f2bf(a[r] + bias);  // no relu here
            }
        }
    }
}

// ---------------- K3: recurrence scan, 1 row per block ----------------------
// 1024 blocks x 128 thr (2 waves): dir = bid>>9, batch row b = bid&511.
// Whh row o in 32 float4 VGPRs (fp32, no unpack); h fp32 in LDS (broadcast).
__global__ __launch_bounds__(128) void k_scan(
    const unsigned short* __restrict__ xw,
    const float* __restrict__ whhf, const float* __restrict__ whhb,
    const int* __restrict__ norder, const float* __restrict__ nw,
    float* __restrict__ accf, float* __restrict__ accb)
{
    __shared__ __align__(16) float hbuf[HD];
    __shared__ float partial[2];
    int tid = threadIdx.x, o = tid, wv = tid >> 6, l = tid & 63;
    int dir = blockIdx.x >> 9, b = blockIdx.x & 511;
    const float* whh = dir ? whhb : whhf;
    float* acc = dir ? accb : accf;
    int segoff = dir ? (HS + HD) : HS;   // 384 : 256

    float4 wr[32];
    const float4* wp = (const float4*)(whh + (size_t)o * HD);  // 512B aligned
    #pragma unroll
    for (int i = 0; i < 32; ++i) wr[i] = wp[i];
    float wno = nw[(size_t)norder[b] * D + segoff + o];
    hbuf[o] = 0.f;
    const unsigned short* xp = xw + ((size_t)dir * BT + (size_t)b * T) * HD + o;
    int t = dir ? (T - 1) : 0, dt = dir ? -1 : 1;
    unsigned short x0 = xp[(size_t)t * HD];
    __syncthreads();

    const float4* h4 = (const float4*)hbuf;
    for (int step = 0; step < T; ++step) {
        float a = bf2f(x0);   // xw already includes b_ih + b_hh
        #pragma unroll
        for (int i = 0; i < 32; ++i) {
            float4 h = h4[i], ww = wr[i];
            a += h.x * ww.x + h.y * ww.y + h.z * ww.z + h.w * ww.w;
        }
        a = fmaxf(a, 0.f);
        int tn = t + dt;
        unsigned short px = 0;
        if (step + 1 < T) px = xp[(size_t)tn * HD];   // prefetch next xw
        // routed-dot partial (registers only — no LDS h read)
        float p = a * wno;
        #pragma unroll
        for (int off = 32; off; off >>= 1) p += __shfl_xor(p, off);
        if (l == 0) partial[wv] = p;
        __syncthreads();          // A: all h_{t-1} reads done; partial visible
        hbuf[o] = a;
        if (tid == 0) acc[(size_t)b * T + t] = partial[0] + partial[1];
        __syncthreads();          // B: h_t visible
        x0 = px; t = tn;
    }
}

// ---------------- K4: out = relu(statd[b] + accf + accb) -> FP32 ------------
__global__ __launch_bounds__(256) void k_final(
    const float* __restrict__ statd, const float* __restrict__ accf,
    const float* __restrict__ accb, float* __restrict__ out)
{
    int idx = blockIdx.x * 256 + threadIdx.x;
    if (idx < BT) {
        int b = idx / T;
        out[idx] = fmaxf(statd[b] + accf[idx] + accb[idx], 0.f);
    }
}

extern "C" void kernel_launch(void* const* d_in, const int* in_sizes, int n_in,
                              void* d_out, int out_size, void* d_ws, size_t ws_size,
                              hipStream_t stream)
{
    const float* x_static  = (const float*)d_in[0];
    const float* x_dynamic = (const float*)d_in[1];
    const int*   norder    = (const int*)d_in[2];
    const float* w_s1   = (const float*)d_in[3];
    const float* b_s1   = (const float*)d_in[4];
    const float* w_s2   = (const float*)d_in[5];
    const float* b_s2   = (const float*)d_in[6];
    const float* w_dyn  = (const float*)d_in[7];
    const float* b_dyn  = (const float*)d_in[8];
    const float* w_ih_f = (const float*)d_in[9];
    const float* w_hh_f = (const float*)d_in[10];
    const float* b_ih_f = (const float*)d_in[11];
    const float* b_hh_f = (const float*)d_in[12];
    const float* w_ih_b = (const float*)d_in[13];
    const float* w_hh_b = (const float*)d_in[14];
    const float* b_ih_b = (const float*)d_in[15];
    const float* b_hh_b = (const float*)d_in[16];
    const float* nw     = (const float*)d_in[17];
    const float* nb     = (const float*)d_in[18];
    float* out = (float*)d_out;

    // ws: statd 2KB | accf 400KB | accb 400KB | xw 52.4MB
    char* ws = (char*)d_ws;
    float* statd = (float*)ws;
    float* accf  = (float*)(ws + 2048);
    float* accb  = (float*)(ws + 2048 + (size_t)BT * 4);
    unsigned short* xw = (unsigned short*)(ws + 2048 + (size_t)BT * 8);

    hipLaunchKernelGGL(k_static, dim3(B), dim3(256), 0, stream,
                       x_static, w_s1, b_s1, w_s2, b_s2, norder, nw, nb, statd);
    hipLaunchKernelGGL(k_dxw, dim3(BT / 64), dim3(256), 0, stream,
                       x_dynamic, w_dyn, b_dyn,
                       w_ih_f, b_ih_f, b_hh_f, w_ih_b, b_ih_b, b_hh_b, xw);
    hipLaunchKernelGGL(k_scan, dim3(1024), dim3(128), 0, stream,
                       xw, w_hh_f, w_hh_b, norder, nw, accf, accb);
    hipLaunchKernelGGL(k_final, dim3((BT + 255) / 256), dim3(256), 0, stream,
                       statd, accf, accb, out);
}

// Round 8
// 444.802 us; speedup vs baseline: 16.5864x; 1.0653x over previous
//
#include <hip/hip_runtime.h>
#include <cstdint>

// MTNN: static MLP + dyn proj + biRNN(relu) + routed per-trial dot.
// B=512,T=200,SI=100,DI=68,HS=256,HD=128,D=512,K=1. fp32 in, fp32 out.
// R7->R8: k_scan was LDS-instr-pipe bound (256 broadcast ds_read_b128/CU/step
// = 2857 cyc/step measured). New scan: 1 wave/row, fp16 h, K-quartered reads
// (4 b128), v_dot2_f32_f16 MACs, shfl combine, zero barriers. Weights
// pre-converted once by k_prep (k_dxw had per-block conversion waste).
constexpr int B = 512, T = 200, SI = 100, DI = 68, HS = 256, HD = 128, D = 512;
constexpr int BT = B * T;   // 102400

typedef __attribute__((ext_vector_type(8))) short short8;     // 8 bf16 (4 VGPRs)
typedef __attribute__((ext_vector_type(4))) float floatx4;    // MFMA C/D
typedef _Float16 half2t __attribute__((ext_vector_type(2)));  // packed fp16 pair

#define DEV __device__ __forceinline__

DEV unsigned short f2bf(float f) {
    unsigned int x = __builtin_bit_cast(unsigned int, f);
    x += 0x7fffu + ((x >> 16) & 1u);   // RNE
    return (unsigned short)(x >> 16);
}
DEV unsigned short f2h(float f) {
    return __builtin_bit_cast(unsigned short, (_Float16)f);
}
DEV half2t u2h2(unsigned int u) { return __builtin_bit_cast(half2t, u); }

#if defined(__has_builtin)
#  if __has_builtin(__builtin_amdgcn_fdot2)
#    define FDOT2(w, h, c) __builtin_amdgcn_fdot2((w), (h), (c), false)
#  endif
#endif
#ifndef FDOT2
DEV float fdot2_sw(half2t a, half2t b, float c) {
    return c + (float)a[0] * (float)b[0] + (float)a[1] * (float)b[1];
}
#  define FDOT2(w, h, c) fdot2_sw((w), (h), (c))
#endif

// a += dot(8 fp16 in w-uint4, 8 fp16 in h-uint4), fp32 accumulate
DEV float acc8(float a, const uint4& w, const uint4& h) {
    a = FDOT2(u2h2(w.x), u2h2(h.x), a);
    a = FDOT2(u2h2(w.y), u2h2(h.y), a);
    a = FDOT2(u2h2(w.z), u2h2(h.z), a);
    a = FDOT2(u2h2(w.w), u2h2(h.w), a);
    return a;
}

// ---------------- K0: one-time weight conversion ----------------------------
// wdyn_bf[128][96] bf16 (zero-pad K 68->96) | wih_bf[2][128][128] bf16 |
// whh_h[2][128][128] fp16
__global__ __launch_bounds__(256) void k_prep(
    const float* __restrict__ wdyn,
    const float* __restrict__ wihf, const float* __restrict__ wihb,
    const float* __restrict__ whhf, const float* __restrict__ whhb,
    unsigned short* __restrict__ wdyn_bf, unsigned short* __restrict__ wih_bf,
    unsigned short* __restrict__ whh_h)
{
    int gid = blockIdx.x * 256 + threadIdx.x, gs = gridDim.x * 256;
    for (int i = gid; i < HD * 96; i += gs) {
        int r = i / 96, c = i - r * 96;
        wdyn_bf[i] = (c < DI) ? f2bf(wdyn[r * DI + c]) : 0;
    }
    for (int i = gid; i < 2 * HD * HD; i += gs) {
        const float* src = (i < HD * HD) ? wihf : wihb;
        wih_bf[i] = f2bf(src[i & (HD * HD - 1)]);
    }
    for (int i = gid; i < 2 * HD * HD; i += gs) {
        const float* src = (i < HD * HD) ? whhf : whhb;
        whh_h[i] = f2h(src[i & (HD * HD - 1)]);
    }
}

// ---------------- K1: static branch + static segment of routed dot ----------
__global__ __launch_bounds__(256) void k_static(
    const float* __restrict__ xs_g, const float* __restrict__ w1,
    const float* __restrict__ b1, const float* __restrict__ w2,
    const float* __restrict__ b2, const int* __restrict__ norder,
    const float* __restrict__ nw, const float* __restrict__ nb,
    float* __restrict__ statd)
{
    __shared__ __align__(16) float xs[SI];
    __shared__ __align__(16) float s1[HS];
    __shared__ __align__(16) float red[256];
    int b = blockIdx.x, t = threadIdx.x;
    if (t < SI) xs[t] = xs_g[b * SI + t];
    __syncthreads();
    float a = b1[t];
    const float4* w = (const float4*)(w1 + t * SI);
    const float4* xp4 = (const float4*)xs;
    #pragma unroll
    for (int i = 0; i < SI / 4; ++i) {
        float4 ww = w[i]; float4 xx = xp4[i];
        a += xx.x * ww.x + xx.y * ww.y + xx.z * ww.z + xx.w * ww.w;
    }
    s1[t] = fmaxf(a, 0.f);
    __syncthreads();
    float a2 = b2[t];
    const float4* w2p = (const float4*)(w2 + t * HS);
    const float4* s1p = (const float4*)s1;
    #pragma unroll 8
    for (int i = 0; i < HS / 4; ++i) {
        float4 ww = w2p[i]; float4 s = s1p[i];
        a2 += s.x * ww.x + s.y * ww.y + s.z * ww.z + s.w * ww.w;
    }
    float sv = fmaxf(a2, 0.f);
    int n = norder[b];
    red[t] = sv * nw[(size_t)n * D + t];
    __syncthreads();
    for (int s = 128; s > 0; s >>= 1) {
        if (t < s) red[t] += red[t + s];
        __syncthreads();
    }
    if (t == 0) statd[b] = red[0] + nb[n];
}

// ---------------- K2: d + ih-projection via MFMA (prepped weights) ----------
// 1600 blocks x 256 thr. Block = 64 BT-rows; wave w owns rows [w*16,w*16+16).
// P2: d = relu(x @ Wdyn^T + bd) (K=96 padded); P3: xw_z = d @ Wih_z^T + bias_z.
// B-frags loaded directly as bf16 short8 (no per-block conversion). xw: fp16.
__global__ __launch_bounds__(256) void k_dxw(
    const float* __restrict__ xd,
    const unsigned short* __restrict__ wdyn_bf, const float* __restrict__ bdyn,
    const unsigned short* __restrict__ wih_bf,
    const float* __restrict__ bihf, const float* __restrict__ bhhf,
    const float* __restrict__ bihb, const float* __restrict__ bhhb,
    unsigned short* __restrict__ xw)
{
    __shared__ __align__(16) unsigned short xb[64][104];  // x bf16, K 0..95 (+pad)
    __shared__ __align__(16) unsigned short dl[64][136];  // d bf16, 128 cols (+pad)
    int tid = threadIdx.x;
    int R0 = blockIdx.x * 64;
    for (int i = tid; i < 64 * 104; i += 256) ((unsigned short*)xb)[i] = 0;
    __syncthreads();
    for (int i = tid; i < 64 * DI; i += 256) {
        int r = i / DI, c = i - r * DI;
        xb[r][c] = f2bf(xd[(size_t)(R0 + r) * DI + c]);
    }
    __syncthreads();

    int lane = tid & 63, w = tid >> 6;
    int ln = lane & 15, q = lane >> 4;

    // ---- P2 ----
    short8 af[3];
    #pragma unroll
    for (int c = 0; c < 3; ++c)
        af[c] = *(const short8*)&xb[w * 16 + ln][c * 32 + q * 8];
    #pragma unroll
    for (int j = 0; j < 8; ++j) {
        int n = j * 16 + ln;
        floatx4 a = {0.f, 0.f, 0.f, 0.f};
        #pragma unroll
        for (int c = 0; c < 3; ++c) {
            short8 bf = *(const short8*)(wdyn_bf + (size_t)n * 96 + c * 32 + q * 8);
            a = __builtin_amdgcn_mfma_f32_16x16x32_bf16(af[c], bf, a, 0, 0, 0);
        }
        float bd = bdyn[n];
        #pragma unroll
        for (int r = 0; r < 4; ++r) {
            float v = fmaxf(a[r] + bd, 0.f);              // C/D: row=q*4+r, col=n
            dl[w * 16 + q * 4 + r][n] = f2bf(v);
        }
    }
    __syncthreads();

    // ---- P3 (both directions) ----
    short8 df[4];
    #pragma unroll
    for (int c = 0; c < 4; ++c)
        df[c] = *(const short8*)&dl[w * 16 + ln][c * 32 + q * 8];
    #pragma unroll
    for (int z = 0; z < 2; ++z) {
        const float* bi = z ? bihb : bihf;
        const float* bh = z ? bhhb : bhhf;
        const unsigned short* wih = wih_bf + (size_t)z * HD * HD;
        unsigned short* outp = xw + (size_t)z * BT * HD;
        #pragma unroll
        for (int j = 0; j < 8; ++j) {
            int n = j * 16 + ln;
            floatx4 a = {0.f, 0.f, 0.f, 0.f};
            #pragma unroll
            for (int c = 0; c < 4; ++c) {
                short8 bf = *(const short8*)(wih + (size_t)n * HD + c * 32 + q * 8);
                a = __builtin_amdgcn_mfma_f32_16x16x32_bf16(df[c], bf, a, 0, 0, 0);
            }
            float bias = bi[n] + bh[n];
            #pragma unroll
            for (int r = 0; r < 4; ++r) {
                int row = R0 + w * 16 + q * 4 + r;
                outp[(size_t)row * HD + n] = f2h(a[r] + bias);  // fp16, no relu
            }
        }
    }
}

// ---------------- K3: recurrence scan, 1 wave per row-scan ------------------
// 1024 blocks x 64 thr: dir=bid>>9, b=bid&511. Lane (qt=l>>4, li=l&15):
// partial dots over K-quarter qt for 8 outputs o=li*8+j via v_dot2_f32_f16,
// combine via shfl_xor(16|32), relu, 16 lanes write h (fp16) back as b128.
// No __syncthreads anywhere (single wave). xw read: 1 dwordx4/step, 2-deep PF.
__global__ __launch_bounds__(64, 1) void k_scan(
    const unsigned short* __restrict__ xw, const unsigned short* __restrict__ whh_h,
    const int* __restrict__ norder, const float* __restrict__ nw,
    float* __restrict__ accf, float* __restrict__ accb)
{
    __shared__ __align__(16) unsigned int hpk[64];   // 128 fp16 h values
    int l = threadIdx.x, qt = l >> 4, li = l & 15;
    int dir = blockIdx.x >> 9, b = blockIdx.x & 511;
    const unsigned short* wsrc = whh_h + (size_t)dir * HD * HD;
    float* acc = dir ? accb : accf;
    int segoff = dir ? (HS + HD) : HS;   // 384 : 256

    // whh rows o=li*8+j, K-quarter qt -> 8x4 uint4 (128 VGPRs, fp16 packed)
    uint4 wreg[8][4];
    #pragma unroll
    for (int j = 0; j < 8; ++j) {
        const uint4* p = (const uint4*)(wsrc + (size_t)(li * 8 + j) * HD + qt * 32);
        #pragma unroll
        for (int c = 0; c < 4; ++c) wreg[j][c] = p[c];
    }
    int n = norder[b];
    float wnv[8];
    {
        const float4* p = (const float4*)(nw + (size_t)n * D + segoff + li * 8);
        float4 v0 = p[0], v1 = p[1];
        wnv[0] = v0.x; wnv[1] = v0.y; wnv[2] = v0.z; wnv[3] = v0.w;
        wnv[4] = v1.x; wnv[5] = v1.y; wnv[6] = v1.z; wnv[7] = v1.w;
    }
    hpk[l] = 0u;   // h0 = 0

    const unsigned short* xp = xw + ((size_t)dir * BT + (size_t)b * T) * HD + li * 8;
    int t = dir ? (T - 1) : 0, dt = dir ? -1 : 1;
    uint4 x0 = *(const uint4*)(xp + (size_t)t * HD);
    uint4 x1 = *(const uint4*)(xp + (size_t)(t + dt) * HD);   // T >= 2
    const uint4* hq = (const uint4*)hpk + qt * 4;   // this lane's K-quarter

    for (int step = 0; step < T; ++step) {
        uint4 h0 = hq[0], h1 = hq[1], h2v = hq[2], h3 = hq[3];
        float a[8];
        // init with xw (fp16, includes b_ih+b_hh) on quarter 0 only
        #pragma unroll
        for (int j = 0; j < 8; ++j) {
            unsigned int xd_ = (j < 2) ? x0.x : (j < 4) ? x0.y : (j < 6) ? x0.z : x0.w;
            float xv = (float)u2h2(xd_)[j & 1];
            a[j] = (qt == 0) ? xv : 0.f;
        }
        #pragma unroll
        for (int j = 0; j < 8; ++j) {
            a[j] = acc8(a[j], wreg[j][0], h0);
            a[j] = acc8(a[j], wreg[j][1], h1);
            a[j] = acc8(a[j], wreg[j][2], h2v);
            a[j] = acc8(a[j], wreg[j][3], h3);
        }
        // combine the 4 K-quarters (lanes xor 16, 32)
        #pragma unroll
        for (int j = 0; j < 8; ++j) {
            a[j] += __shfl_xor(a[j], 16);
            a[j] += __shfl_xor(a[j], 32);
            a[j] = fmaxf(a[j], 0.f);
        }
        // prefetch xw for step+2
        int t2 = t + 2 * dt;
        uint4 px = x1;
        if (step + 2 < T) px = *(const uint4*)(xp + (size_t)t2 * HD);
        // write h back (all lanes hold identical full a[]; quarter 0 writes)
        if (qt == 0) {
            uint4 hp;
            hp.x = (unsigned int)f2h(a[0]) | ((unsigned int)f2h(a[1]) << 16);
            hp.y = (unsigned int)f2h(a[2]) | ((unsigned int)f2h(a[3]) << 16);
            hp.z = (unsigned int)f2h(a[4]) | ((unsigned int)f2h(a[5]) << 16);
            hp.w = (unsigned int)f2h(a[6]) | ((unsigned int)f2h(a[7]) << 16);
            ((uint4*)hpk)[li] = hp;
        }
        // P4: routed dot. Lane partial over its 8 outputs, reduce across li.
        float p = a[0] * wnv[0] + a[1] * wnv[1] + a[2] * wnv[2] + a[3] * wnv[3]
                + a[4] * wnv[4] + a[5] * wnv[5] + a[6] * wnv[6] + a[7] * wnv[7];
        p += __shfl_xor(p, 1);
        p += __shfl_xor(p, 2);
        p += __shfl_xor(p, 4);
        p += __shfl_xor(p, 8);
        if (l == 0) acc[(size_t)b * T + t] = p;
        x0 = x1; x1 = px; t += dt;
    }
}

// ---------------- K4: out = relu(statd[b] + accf + accb) -> FP32 ------------
__global__ __launch_bounds__(256) void k_final(
    const float* __restrict__ statd, const float* __restrict__ accf,
    const float* __restrict__ accb, float* __restrict__ out)
{
    int idx = blockIdx.x * 256 + threadIdx.x;
    if (idx < BT) {
        int b = idx / T;
        out[idx] = fmaxf(statd[b] + accf[idx] + accb[idx], 0.f);
    }
}

extern "C" void kernel_launch(void* const* d_in, const int* in_sizes, int n_in,
                              void* d_out, int out_size, void* d_ws, size_t ws_size,
                              hipStream_t stream)
{
    const float* x_static  = (const float*)d_in[0];
    const float* x_dynamic = (const float*)d_in[1];
    const int*   norder    = (const int*)d_in[2];
    const float* w_s1   = (const float*)d_in[3];
    const float* b_s1   = (const float*)d_in[4];
    const float* w_s2   = (const float*)d_in[5];
    const float* b_s2   = (const float*)d_in[6];
    const float* w_dyn  = (const float*)d_in[7];
    const float* b_dyn  = (const float*)d_in[8];
    const float* w_ih_f = (const float*)d_in[9];
    const float* w_hh_f = (const float*)d_in[10];
    const float* b_ih_f = (const float*)d_in[11];
    const float* b_hh_f = (const float*)d_in[12];
    const float* w_ih_b = (const float*)d_in[13];
    const float* w_hh_b = (const float*)d_in[14];
    const float* b_ih_b = (const float*)d_in[15];
    const float* b_hh_b = (const float*)d_in[16];
    const float* nw     = (const float*)d_in[17];
    const float* nb     = (const float*)d_in[18];
    float* out = (float*)d_out;

    // ws: statd 2KB | accf 400KB | accb 400KB | xw fp16 52.4MB | prepped wts
    char* ws = (char*)d_ws;
    float* statd = (float*)ws;
    float* accf  = (float*)(ws + 2048);
    float* accb  = (float*)(ws + 2048 + (size_t)BT * 4);
    unsigned short* xw = (unsigned short*)(ws + 2048 + (size_t)BT * 8);
    size_t xw_bytes = (size_t)2 * BT * HD * 2;   // 52.4 MB
    unsigned short* wdyn_bf = (unsigned short*)(ws + 2048 + (size_t)BT * 8 + xw_bytes);
    unsigned short* wih_bf  = wdyn_bf + HD * 96;
    unsigned short* whh_h   = wih_bf + 2 * HD * HD;

    hipLaunchKernelGGL(k_prep, dim3(64), dim3(256), 0, stream,
                       w_dyn, w_ih_f, w_ih_b, w_hh_f, w_hh_b,
                       wdyn_bf, wih_bf, whh_h);
    hipLaunchKernelGGL(k_static, dim3(B), dim3(256), 0, stream,
                       x_static, w_s1, b_s1, w_s2, b_s2, norder, nw, nb, statd);
    hipLaunchKernelGGL(k_dxw, dim3(BT / 64), dim3(256), 0, stream,
                       x_dynamic, wdyn_bf, b_dyn, wih_bf,
                       b_ih_f, b_hh_f, b_ih_b, b_hh_b, xw);
    hipLaunchKernelGGL(k_scan, dim3(1024), dim3(64), 0, stream,
                       xw, whh_h, norder, nw, accf, accb);
    hipLaunchKernelGGL(k_final, dim3((BT + 255) / 256), dim3(256), 0, stream,
                       statd, accf, accb, out);
}

// Round 10
// 409.253 us; speedup vs baseline: 18.0271x; 1.0869x over previous
//
#include <hip/hip_runtime.h>
#include <cstdint>

// MTNN: static MLP + dyn proj + biRNN(relu) + routed per-trial dot.
// B=512,T=200,SI=100,DI=68,HS=256,HD=128,D=512,K=1. fp32 in, fp32 out.
// R8->R9: k_scan rebuilt as MFMA recurrence: 16 batch rows per 1-wave block,
// H_t = relu(XW_t + Whh H_{t-1}) as M=128,N=16,K=128 GEMM (32 mfma/step).
// Whh in A-frag registers; H LDS roundtrip where D-layout writes (b64) land
// exactly in next step's B-frag layout (b128 reads). Zero barriers.
// R9 fix: cvt_pkrtz returns __fp16x2 — bit_cast its native type (compile err).
constexpr int B = 512, T = 200, SI = 100, DI = 68, HS = 256, HD = 128, D = 512;
constexpr int BT = B * T;   // 102400

typedef __attribute__((ext_vector_type(8))) short short8;       // 8 bf16
typedef __attribute__((ext_vector_type(4))) float floatx4;      // MFMA C/D
typedef _Float16 half8 __attribute__((ext_vector_type(8)));     // 8 fp16
typedef _Float16 half2t __attribute__((ext_vector_type(2)));    // fp16 pair

#define DEV __device__ __forceinline__

DEV unsigned short f2bf(float f) {
    unsigned int x = __builtin_bit_cast(unsigned int, f);
    x += 0x7fffu + ((x >> 16) & 1u);   // RNE
    return (unsigned short)(x >> 16);
}
DEV unsigned short f2h(float f) {
    return __builtin_bit_cast(unsigned short, (_Float16)f);
}
DEV half2t u2h2(unsigned int u) { return __builtin_bit_cast(half2t, u); }
DEV unsigned int pkh(float a, float b) {
    return __builtin_bit_cast(unsigned int, __builtin_amdgcn_cvt_pkrtz(a, b));
}

// ---------------- K0: one-time weight conversion ----------------------------
// wdyn_bf[128][96] bf16 (zero-pad K 68->96) | wih_bf[2][128][128] bf16 |
// whh_h[2][128][128] fp16
__global__ __launch_bounds__(256) void k_prep(
    const float* __restrict__ wdyn,
    const float* __restrict__ wihf, const float* __restrict__ wihb,
    const float* __restrict__ whhf, const float* __restrict__ whhb,
    unsigned short* __restrict__ wdyn_bf, unsigned short* __restrict__ wih_bf,
    unsigned short* __restrict__ whh_h)
{
    int gid = blockIdx.x * 256 + threadIdx.x, gs = gridDim.x * 256;
    for (int i = gid; i < HD * 96; i += gs) {
        int r = i / 96, c = i - r * 96;
        wdyn_bf[i] = (c < DI) ? f2bf(wdyn[r * DI + c]) : 0;
    }
    for (int i = gid; i < 2 * HD * HD; i += gs) {
        const float* src = (i < HD * HD) ? wihf : wihb;
        wih_bf[i] = f2bf(src[i & (HD * HD - 1)]);
    }
    for (int i = gid; i < 2 * HD * HD; i += gs) {
        const float* src = (i < HD * HD) ? whhf : whhb;
        whh_h[i] = f2h(src[i & (HD * HD - 1)]);
    }
}

// ---------------- K1: static branch + static segment of routed dot ----------
__global__ __launch_bounds__(256) void k_static(
    const float* __restrict__ xs_g, const float* __restrict__ w1,
    const float* __restrict__ b1, const float* __restrict__ w2,
    const float* __restrict__ b2, const int* __restrict__ norder,
    const float* __restrict__ nw, const float* __restrict__ nb,
    float* __restrict__ statd)
{
    __shared__ __align__(16) float xs[SI];
    __shared__ __align__(16) float s1[HS];
    __shared__ __align__(16) float red[256];
    int b = blockIdx.x, t = threadIdx.x;
    if (t < SI) xs[t] = xs_g[b * SI + t];
    __syncthreads();
    float a = b1[t];
    const float4* w = (const float4*)(w1 + t * SI);
    const float4* xp4 = (const float4*)xs;
    #pragma unroll
    for (int i = 0; i < SI / 4; ++i) {
        float4 ww = w[i]; float4 xx = xp4[i];
        a += xx.x * ww.x + xx.y * ww.y + xx.z * ww.z + xx.w * ww.w;
    }
    s1[t] = fmaxf(a, 0.f);
    __syncthreads();
    float a2 = b2[t];
    const float4* w2p = (const float4*)(w2 + t * HS);
    const float4* s1p = (const float4*)s1;
    #pragma unroll 8
    for (int i = 0; i < HS / 4; ++i) {
        float4 ww = w2p[i]; float4 s = s1p[i];
        a2 += s.x * ww.x + s.y * ww.y + s.z * ww.z + s.w * ww.w;
    }
    float sv = fmaxf(a2, 0.f);
    int n = norder[b];
    red[t] = sv * nw[(size_t)n * D + t];
    __syncthreads();
    for (int s = 128; s > 0; s >>= 1) {
        if (t < s) red[t] += red[t + s];
        __syncthreads();
    }
    if (t == 0) statd[b] = red[0] + nb[n];
}

// ---------------- K2: d + ih-projection via MFMA (prepped weights) ----------
__global__ __launch_bounds__(256) void k_dxw(
    const float* __restrict__ xd,
    const unsigned short* __restrict__ wdyn_bf, const float* __restrict__ bdyn,
    const unsigned short* __restrict__ wih_bf,
    const float* __restrict__ bihf, const float* __restrict__ bhhf,
    const float* __restrict__ bihb, const float* __restrict__ bhhb,
    unsigned short* __restrict__ xw)
{
    __shared__ __align__(16) unsigned short xb[64][104];  // x bf16, K 0..95 (+pad)
    __shared__ __align__(16) unsigned short dl[64][136];  // d bf16, 128 cols (+pad)
    int tid = threadIdx.x;
    int R0 = blockIdx.x * 64;
    for (int i = tid; i < 64 * 104; i += 256) ((unsigned short*)xb)[i] = 0;
    __syncthreads();
    for (int i = tid; i < 64 * DI; i += 256) {
        int r = i / DI, c = i - r * DI;
        xb[r][c] = f2bf(xd[(size_t)(R0 + r) * DI + c]);
    }
    __syncthreads();

    int lane = tid & 63, w = tid >> 6;
    int ln = lane & 15, q = lane >> 4;

    // ---- P2 ----
    short8 af[3];
    #pragma unroll
    for (int c = 0; c < 3; ++c)
        af[c] = *(const short8*)&xb[w * 16 + ln][c * 32 + q * 8];
    #pragma unroll
    for (int j = 0; j < 8; ++j) {
        int n = j * 16 + ln;
        floatx4 a = {0.f, 0.f, 0.f, 0.f};
        #pragma unroll
        for (int c = 0; c < 3; ++c) {
            short8 bf = *(const short8*)(wdyn_bf + (size_t)n * 96 + c * 32 + q * 8);
            a = __builtin_amdgcn_mfma_f32_16x16x32_bf16(af[c], bf, a, 0, 0, 0);
        }
        float bd = bdyn[n];
        #pragma unroll
        for (int r = 0; r < 4; ++r) {
            float v = fmaxf(a[r] + bd, 0.f);              // C/D: row=q*4+r, col=n
            dl[w * 16 + q * 4 + r][n] = f2bf(v);
        }
    }
    __syncthreads();

    // ---- P3 (both directions) ----
    short8 df[4];
    #pragma unroll
    for (int c = 0; c < 4; ++c)
        df[c] = *(const short8*)&dl[w * 16 + ln][c * 32 + q * 8];
    #pragma unroll
    for (int z = 0; z < 2; ++z) {
        const float* bi = z ? bihb : bihf;
        const float* bh = z ? bhhb : bhhf;
        const unsigned short* wih = wih_bf + (size_t)z * HD * HD;
        unsigned short* outp = xw + (size_t)z * BT * HD;
        #pragma unroll
        for (int j = 0; j < 8; ++j) {
            int n = j * 16 + ln;
            floatx4 a = {0.f, 0.f, 0.f, 0.f};
            #pragma unroll
            for (int c = 0; c < 4; ++c) {
                short8 bf = *(const short8*)(wih + (size_t)n * HD + c * 32 + q * 8);
                a = __builtin_amdgcn_mfma_f32_16x16x32_bf16(df[c], bf, a, 0, 0, 0);
            }
            float bias = bi[n] + bh[n];
            #pragma unroll
            for (int r = 0; r < 4; ++r) {
                int row = R0 + w * 16 + q * 4 + r;
                outp[(size_t)row * HD + n] = f2h(a[r] + bias);  // fp16, no relu
            }
        }
    }
}

// ---------------- K3: MFMA recurrence, 16 rows per 1-wave block -------------
// 64 blocks x 64 thr. dir = bid>>5, b0 = (bid&31)*16.
// Step: H_t[o][row] = relu(XW_t[o][row] + Whh @ H_{t-1}), o-tiles j=0..7,
// K-chunks c=0..3. A=Whh (fp16 frags, 128 VGPRs, loaded once), B=H from LDS
// (b128 = B-frag layout), D writes (4 consecutive o) -> ds_write_b64 back
// into B-layout. Single wave: DS pipe in-order, no barriers.
__global__ __launch_bounds__(64, 1) void k_scan(
    const unsigned short* __restrict__ xw, const unsigned short* __restrict__ whh_h,
    const int* __restrict__ norder, const float* __restrict__ nw,
    float* __restrict__ accf, float* __restrict__ accb)
{
    __shared__ __align__(16) unsigned short H[16 * 136];   // fp16, row pad 136
    int l = threadIdx.x, ln = l & 15, q = l >> 4;
    int dir = blockIdx.x >> 5, b0 = (blockIdx.x & 31) * 16;
    const unsigned short* whh = whh_h + (size_t)dir * HD * HD;
    float* acc = dir ? accb : accf;
    int segoff = dir ? (HS + HD) : HS;   // 384 : 256

    // A-frags: Whh[o = j*16+ln][k = c*32+q*8 .. +7], fp16 (128 VGPRs)
    half8 wfr[8][4];
    #pragma unroll
    for (int j = 0; j < 8; ++j)
        #pragma unroll
        for (int c = 0; c < 4; ++c)
            wfr[j][c] = *(const half8*)(whh + (size_t)(j * 16 + ln) * HD + c * 32 + q * 8);

    // routed weights for this lane's (row=ln, o=j*16+q*4..+3)
    int nrow = norder[b0 + ln];
    float4 wnl[8];
    #pragma unroll
    for (int j = 0; j < 8; ++j)
        wnl[j] = *(const float4*)(nw + (size_t)nrow * D + segoff + j * 16 + q * 4);

    // H_0 = 0
    for (int i = l; i < 16 * 136; i += 64) H[i] = 0;

    // xw base for this lane's batch row; C-init values o=j*16+q*4..+3
    const unsigned short* xp = xw + ((size_t)dir * BT + (size_t)(b0 + ln) * T) * HD;
    int t = dir ? (T - 1) : 0, dt = dir ? -1 : 1;
    uint2 xc[8], xn[8];
    #pragma unroll
    for (int j = 0; j < 8; ++j)
        xc[j] = *(const uint2*)(xp + (size_t)t * HD + j * 16 + q * 4);
    #pragma unroll
    for (int j = 0; j < 8; ++j)
        xn[j] = *(const uint2*)(xp + (size_t)(t + dt) * HD + j * 16 + q * 4);

    for (int step = 0; step < T; ++step) {
        // B-frags: H_{t-1}[row=ln][k = c*32+q*8 .. +7]
        half8 hf[4];
        #pragma unroll
        for (int c = 0; c < 4; ++c)
            hf[c] = *(const half8*)&H[ln * 136 + c * 32 + q * 8];
        // 8 o-tiles: C-init from xw, 4 chained mfma each
        floatx4 dcc[8];
        #pragma unroll
        for (int j = 0; j < 8; ++j) {
            half2t lo = u2h2(xc[j].x), hi = u2h2(xc[j].y);
            floatx4 a = {(float)lo[0], (float)lo[1], (float)hi[0], (float)hi[1]};
            #pragma unroll
            for (int c = 0; c < 4; ++c)
                a = __builtin_amdgcn_mfma_f32_16x16x32_f16(wfr[j][c], hf[c], a, 0, 0, 0);
            dcc[j] = a;
        }
        // prefetch xw for step+2
        int t2 = t + 2 * dt;
        uint2 px[8];
        if (step + 2 < T) {
            #pragma unroll
            for (int j = 0; j < 8; ++j)
                px[j] = *(const uint2*)(xp + (size_t)t2 * HD + j * 16 + q * 4);
        } else {
            #pragma unroll
            for (int j = 0; j < 8; ++j) px[j] = xn[j];
        }
        // relu, write H_t (lane ln, o = j*16+q*4..+3 -> b64), routed partial
        float p = 0.f;
        #pragma unroll
        for (int j = 0; j < 8; ++j) {
            float r0 = fmaxf(dcc[j][0], 0.f), r1 = fmaxf(dcc[j][1], 0.f);
            float r2 = fmaxf(dcc[j][2], 0.f), r3 = fmaxf(dcc[j][3], 0.f);
            uint2 hp;
            hp.x = pkh(r0, r1);
            hp.y = pkh(r2, r3);
            *(uint2*)&H[ln * 136 + j * 16 + q * 4] = hp;
            float4 wn4 = wnl[j];
            p += r0 * wn4.x + r1 * wn4.y + r2 * wn4.z + r3 * wn4.w;
        }
        // reduce over q (lanes ln, ln+16, ln+32, ln+48)
        p += __shfl_xor(p, 16);
        p += __shfl_xor(p, 32);
        if (l < 16) acc[(size_t)(b0 + ln) * T + t] = p;
        #pragma unroll
        for (int j = 0; j < 8; ++j) { xc[j] = xn[j]; xn[j] = px[j]; }
        t += dt;
    }
}

// ---------------- K4: out = relu(statd[b] + accf + accb) -> FP32 ------------
__global__ __launch_bounds__(256) void k_final(
    const float* __restrict__ statd, const float* __restrict__ accf,
    const float* __restrict__ accb, float* __restrict__ out)
{
    int idx = blockIdx.x * 256 + threadIdx.x;
    if (idx < BT) {
        int b = idx / T;
        out[idx] = fmaxf(statd[b] + accf[idx] + accb[idx], 0.f);
    }
}

extern "C" void kernel_launch(void* const* d_in, const int* in_sizes, int n_in,
                              void* d_out, int out_size, void* d_ws, size_t ws_size,
                              hipStream_t stream)
{
    const float* x_static  = (const float*)d_in[0];
    const float* x_dynamic = (const float*)d_in[1];
    const int*   norder    = (const int*)d_in[2];
    const float* w_s1   = (const float*)d_in[3];
    const float* b_s1   = (const float*)d_in[4];
    const float* w_s2   = (const float*)d_in[5];
    const float* b_s2   = (const float*)d_in[6];
    const float* w_dyn  = (const float*)d_in[7];
    const float* b_dyn  = (const float*)d_in[8];
    const float* w_ih_f = (const float*)d_in[9];
    const float* w_hh_f = (const float*)d_in[10];
    const float* b_ih_f = (const float*)d_in[11];
    const float* b_hh_f = (const float*)d_in[12];
    const float* w_ih_b = (const float*)d_in[13];
    const float* w_hh_b = (const float*)d_in[14];
    const float* b_ih_b = (const float*)d_in[15];
    const float* b_hh_b = (const float*)d_in[16];
    const float* nw     = (const float*)d_in[17];
    const float* nb     = (const float*)d_in[18];
    float* out = (float*)d_out;

    // ws: statd 2KB | accf 400KB | accb 400KB | xw fp16 52.4MB | prepped wts
    char* ws = (char*)d_ws;
    float* statd = (float*)ws;
    float* accf  = (float*)(ws + 2048);
    float* accb  = (float*)(ws + 2048 + (size_t)BT * 4);
    unsigned short* xw = (unsigned short*)(ws + 2048 + (size_t)BT * 8);
    size_t xw_bytes = (size_t)2 * BT * HD * 2;   // 52.4 MB
    unsigned short* wdyn_bf = (unsigned short*)(ws + 2048 + (size_t)BT * 8 + xw_bytes);
    unsigned short* wih_bf  = wdyn_bf + HD * 96;
    unsigned short* whh_h   = wih_bf + 2 * HD * HD;

    hipLaunchKernelGGL(k_prep, dim3(64), dim3(256), 0, stream,
                       w_dyn, w_ih_f, w_ih_b, w_hh_f, w_hh_b,
                       wdyn_bf, wih_bf, whh_h);
    hipLaunchKernelGGL(k_static, dim3(B), dim3(256), 0, stream,
                       x_static, w_s1, b_s1, w_s2, b_s2, norder, nw, nb, statd);
    hipLaunchKernelGGL(k_dxw, dim3(BT / 64), dim3(256), 0, stream,
                       x_dynamic, wdyn_bf, b_dyn, wih_bf,
                       b_ih_f, b_hh_f, b_ih_b, b_hh_b, xw);
    hipLaunchKernelGGL(k_scan, dim3(64), dim3(64), 0, stream,
                       xw, whh_h, norder, nw, accf, accb);
    hipLaunchKernelGGL(k_final, dim3((BT + 255) / 256), dim3(256), 0, stream,
                       statd, accf, accb, out);
}